// Round 1
// baseline (191.913 us; speedup 1.0000x reference)
//
#include <hip/hip_runtime.h>
#include <hip/hip_bf16.h>
#include <math.h>

// Problem constants (SpatialAxialAttention): B=1,T=2,H=W=16,dim=1024,HEADS=16,DIM_HEAD=64,K=144
#define BTN   2      // B*T
#define NH    16     // heads
#define SEQ   256    // H*W
#define DH    64     // dim head
#define DIMF  1024   // model dim == inner
#define KTOP  144
#define PI_F  3.14159265358979323846f

// ---------------------------------------------------------------------------
// NT GEMM: C[r][o] = sum_c A[r][c] * B[o][c]
// MODE 0: epilogue = split qkv -> axial RoPE on q,k -> scatter to (bt,head,s,d)
// MODE 1: epilogue = + bias, row-major store to out
// Tile: BM=BN=64, BK=16, 256 threads, 4x4 per thread.
// ---------------------------------------------------------------------------
template <int MODE>
__global__ __launch_bounds__(256)
void gemm_nt_kernel(const float* __restrict__ A, const float* __restrict__ B,
                    int Kd, int N,
                    float* __restrict__ qb, float* __restrict__ kb, float* __restrict__ vb,
                    const float* __restrict__ bias, float* __restrict__ out)
{
    __shared__ __align__(16) float As[16][64];
    __shared__ __align__(16) float Bs[16][64];

    const int tid  = threadIdx.x;
    const int row0 = blockIdx.y * 64;
    const int col0 = blockIdx.x * 64;
    const int lr = tid >> 2;         // 0..63  (tile row for loads)
    const int lc = (tid & 3) * 4;    // 0,4,8,12 (k-offset for loads)
    const int ty = tid >> 4;         // 0..15
    const int tx = tid & 15;         // 0..15

    const float* Aptr = A + (size_t)(row0 + lr) * Kd + lc;
    const float* Bptr = B + (size_t)(col0 + lr) * Kd + lc;

    float acc[4][4] = {};

    for (int kt = 0; kt < Kd; kt += 16) {
        const float4 av = *(const float4*)(Aptr + kt);
        const float4 bv = *(const float4*)(Bptr + kt);
        __syncthreads();
        As[lc + 0][lr] = av.x; As[lc + 1][lr] = av.y;
        As[lc + 2][lr] = av.z; As[lc + 3][lr] = av.w;
        Bs[lc + 0][lr] = bv.x; Bs[lc + 1][lr] = bv.y;
        Bs[lc + 2][lr] = bv.z; Bs[lc + 3][lr] = bv.w;
        __syncthreads();
#pragma unroll
        for (int kk = 0; kk < 16; ++kk) {
            const float4 a4 = *(const float4*)&As[kk][ty * 4];
            const float4 b4 = *(const float4*)&Bs[kk][tx * 4];
            const float a[4] = {a4.x, a4.y, a4.z, a4.w};
            const float b[4] = {b4.x, b4.y, b4.z, b4.w};
#pragma unroll
            for (int i = 0; i < 4; ++i)
#pragma unroll
                for (int j = 0; j < 4; ++j)
                    acc[i][j] += a[i] * b[j];
        }
    }

    if (MODE == 0) {
        // qkv epilogue with RoPE. cols = col0 + tx*4 + {0..3}; pairs are (0,1),(2,3).
#pragma unroll
        for (int i = 0; i < 4; ++i) {
            const int r  = row0 + ty * 4 + i;
            const int bt = r >> 8;
            const int s  = r & 255;
            const int hh = s >> 4;
            const int ww = s & 15;
#pragma unroll
            for (int jp = 0; jp < 2; ++jp) {
                const int n    = col0 + tx * 4 + jp * 2;
                const int sec  = n >> 10;      // 0=q,1=k,2=v
                const int oi   = n & 1023;
                const int head = oi >> 6;
                const int d    = oi & 63;      // even
                const float e = acc[i][jp * 2];
                const float o = acc[i][jp * 2 + 1];
                const size_t dst = (((size_t)(bt * NH + head)) * SEQ + s) * DH + d;
                if (sec == 2) {
                    vb[dst] = e; vb[dst + 1] = o;
                } else {
                    int j2; float pos;
                    if (d < 32) { j2 = d >> 1;        pos = -1.f + hh * (2.f / 15.f); }
                    else        { j2 = (d - 32) >> 1; pos = -1.f + ww * (2.f / 15.f); }
                    const float basef = PI_F * (1.f + j2 * (127.f / 15.f));
                    const float f = pos * basef;
                    const float cf = cosf(f), sf = sinf(f);
                    float* dp = (sec == 0) ? qb : kb;
                    dp[dst]     = e * cf - o * sf;
                    dp[dst + 1] = o * cf + e * sf;
                }
            }
        }
    } else {
        // bias + store
#pragma unroll
        for (int i = 0; i < 4; ++i) {
            const int r = row0 + ty * 4 + i;
            const int c = col0 + tx * 4;
            float4 v;
            v.x = acc[i][0] + bias[c + 0];
            v.y = acc[i][1] + bias[c + 1];
            v.z = acc[i][2] + bias[c + 2];
            v.w = acc[i][3] + bias[c + 3];
            *(float4*)(out + (size_t)r * N + c) = v;
        }
    }
}

// ---------------------------------------------------------------------------
// Top-k gathered attention. One wave per query (gq = (bt*16+head)*256+s).
// Phase 1: lanes over keys (lane j handles keys j, j+64, j+128<144).
// Phase 2: lanes over d, coalesced v reads, probs broadcast from LDS.
// Fuses + out_not_top_k and the transpose to (bt, s, head*64+d).
// ---------------------------------------------------------------------------
__global__ __launch_bounds__(256)
void attn_topk_kernel(const float* __restrict__ qb, const float* __restrict__ kb,
                      const float* __restrict__ vb, const int* __restrict__ topk,
                      const float* __restrict__ ontk, float* __restrict__ attn_out)
{
    __shared__ float2 pk[4][KTOP];

    const int wave = threadIdx.x >> 6;
    const int lane = threadIdx.x & 63;
    const int gq   = blockIdx.x * 4 + wave;     // 0..8191
    const int bt   = gq >> 12;
    const int hs   = gq & 4095;
    const int head = hs >> 8;
    const int s    = hs & 255;

    const float* qrow  = qb + (size_t)gq * DH;
    const float* kbase = kb + ((size_t)(bt * NH + head)) * SEQ * DH;
    const float* vbase = vb + ((size_t)(bt * NH + head)) * SEQ * DH;
    const int*   idxp  = topk + (size_t)gq * KTOP;

    // q into registers (wave-uniform addresses)
    float qr[DH];
#pragma unroll
    for (int i = 0; i < DH / 4; ++i) {
        const float4 t = *(const float4*)(qrow + i * 4);
        qr[i * 4 + 0] = t.x; qr[i * 4 + 1] = t.y;
        qr[i * 4 + 2] = t.z; qr[i * 4 + 3] = t.w;
    }

    // phase 1: scores for this lane's keys
    float sc[3];
    int   kidx[3];
#pragma unroll
    for (int t = 0; t < 3; ++t) {
        const int kk = lane + t * 64;
        if (kk < KTOP) {
            const int ki = idxp[kk];
            kidx[t] = ki;
            const float4* krow = (const float4*)(kbase + (size_t)ki * DH);
            float dot = 0.f;
#pragma unroll
            for (int i = 0; i < DH / 4; ++i) {
                const float4 kv = krow[i];
                dot += qr[i * 4 + 0] * kv.x + qr[i * 4 + 1] * kv.y +
                       qr[i * 4 + 2] * kv.z + qr[i * 4 + 3] * kv.w;
            }
            sc[t] = dot * 0.125f;
        } else {
            sc[t] = -1e30f;
            kidx[t] = 0;
        }
    }

    // softmax over 144 values spread across lanes
    float m = fmaxf(fmaxf(sc[0], sc[1]), sc[2]);
#pragma unroll
    for (int off = 32; off; off >>= 1) m = fmaxf(m, __shfl_xor(m, off));
    const float e0 = __expf(sc[0] - m);
    const float e1 = __expf(sc[1] - m);
    const float e2 = (lane < 16) ? __expf(sc[2] - m) : 0.f;
    float ssum = e0 + e1 + e2;
#pragma unroll
    for (int off = 32; off; off >>= 1) ssum += __shfl_xor(ssum, off);
    const float inv = 1.f / ssum;

    pk[wave][lane]      = make_float2(e0 * inv, __int_as_float(kidx[0]));
    pk[wave][lane + 64] = make_float2(e1 * inv, __int_as_float(kidx[1]));
    if (lane < 16)
        pk[wave][lane + 128] = make_float2(e2 * inv, __int_as_float(kidx[2]));
    __syncthreads();

    // phase 2: out[d=lane] = ontk + sum_k p_k * v[idx_k][lane]
    float acc = ontk[(size_t)gq * DH + lane];
#pragma unroll 4
    for (int kk = 0; kk < KTOP; ++kk) {
        const float2 pi = pk[wave][kk];
        acc += pi.x * vbase[(size_t)__float_as_int(pi.y) * DH + lane];
    }
    attn_out[((size_t)bt * SEQ + s) * DIMF + head * DH + lane] = acc;
}

// ---------------------------------------------------------------------------
extern "C" void kernel_launch(void* const* d_in, const int* in_sizes, int n_in,
                              void* d_out, int out_size, void* d_ws, size_t ws_size,
                              hipStream_t stream) {
    const float* x     = (const float*)d_in[0];   // (2,256,1024) rows
    const float* w_qkv = (const float*)d_in[1];   // (3072,1024)
    const float* w_out = (const float*)d_in[2];   // (1024,1024)
    const float* b_out = (const float*)d_in[3];   // (1024,)
    const float* ontk  = (const float*)d_in[4];   // (2,16,256,64)
    const int*   topk  = (const int*)d_in[5];     // (2,16,256,144)
    float* out = (float*)d_out;                   // (2,256,1024)

    // workspace: q,k,v in (bt,head,s,d) + attn_out in (bt,s,head*64+d). 8 MB total.
    float* qb   = (float*)d_ws;
    float* kb   = qb + (size_t)BTN * NH * SEQ * DH;
    float* vb   = kb + (size_t)BTN * NH * SEQ * DH;
    float* attn = vb + (size_t)BTN * NH * SEQ * DH;

    // 1) qkv projection + rope + scatter:  C(512x3072) = x(512x1024) . w_qkv^T
    gemm_nt_kernel<0><<<dim3(3072 / 64, 512 / 64), 256, 0, stream>>>(
        x, w_qkv, DIMF, 3072, qb, kb, vb, nullptr, nullptr);

    // 2) gathered top-k attention (8192 queries, 4 per block)
    attn_topk_kernel<<<8192 / 4, 256, 0, stream>>>(qb, kb, vb, topk, ontk, attn);

    // 3) output projection + bias: out(512x1024) = attn(512x1024) . w_out^T + b
    gemm_nt_kernel<1><<<dim3(1024 / 64, 512 / 64), 256, 0, stream>>>(
        attn, w_out, DIMF, DIMF, nullptr, nullptr, nullptr, b_out, out);
}

// Round 2
// 100.272 us; speedup vs baseline: 1.9139x; 1.9139x over previous
//
#include <hip/hip_runtime.h>
#include <hip/hip_bf16.h>
#include <math.h>

// SpatialAxialAttention: B*T=2, H=W=16, dim=1024, HEADS=16, DIM_HEAD=64, K=144
#define BTN   2
#define NH    16
#define SEQ   256
#define DH    64
#define DIMF  1024
#define KTOP  144
#define PI_F  3.14159265358979323846f

typedef _Float16 half8 __attribute__((ext_vector_type(8)));
typedef _Float16 half4v __attribute__((ext_vector_type(4)));
typedef float f32x4 __attribute__((ext_vector_type(4)));

// ---------------------------------------------------------------------------
// fp32 -> fp16 conversion for x, w_qkv, w_out (one launch, 4 elems/thread)
// ---------------------------------------------------------------------------
#define N0Q (524288 / 4)     // x: 512*1024
#define N1Q (3145728 / 4)    // w_qkv: 3072*1024
#define N2Q (1048576 / 4)    // w_out: 1024*1024
__global__ __launch_bounds__(256)
void cvt3_kernel(const float* __restrict__ a, const float* __restrict__ b,
                 const float* __restrict__ c,
                 _Float16* __restrict__ da, _Float16* __restrict__ db,
                 _Float16* __restrict__ dc)
{
    int q = blockIdx.x * 256 + threadIdx.x;
    const float* s; _Float16* d; int off;
    if (q < N0Q)            { s = a; d = da; off = q; }
    else if (q < N0Q + N1Q) { s = b; d = db; off = q - N0Q; }
    else                    { s = c; d = dc; off = q - (N0Q + N1Q); }
    const float4 v = *(const float4*)(s + (size_t)off * 4);
    half4v h;
    h[0] = (_Float16)v.x; h[1] = (_Float16)v.y;
    h[2] = (_Float16)v.z; h[3] = (_Float16)v.w;
    *(half4v*)(d + (size_t)off * 4) = h;
}

// ---------------------------------------------------------------------------
// fp16 MFMA NT-GEMM: C[r][n] = sum_c A[r][c]*B[n][c], fp32 accumulate.
// 64x64 tile, BK=64, 256 threads (4 waves, 2x2 wave grid of 32x32),
// global_load_lds staging with XOR chunk swizzle (8x16B chunks per row).
// MODE 0: epilogue splits qkv, applies axial RoPE to q,k, scatters to
//         (bt,head,s,d). MODE 1: +bias row-major store.
// ---------------------------------------------------------------------------
template <int MODE, int Kd>
__global__ __launch_bounds__(256)
void gemm_f16_kernel(const _Float16* __restrict__ A, const _Float16* __restrict__ B,
                     int N,
                     float* __restrict__ qb, float* __restrict__ kb, float* __restrict__ vb,
                     const float* __restrict__ bias, float* __restrict__ out)
{
    __shared__ __align__(16) _Float16 As[64 * 64];
    __shared__ __align__(16) _Float16 Bs[64 * 64];

    const int tid  = threadIdx.x;
    const int wave = tid >> 6;
    const int lane = tid & 63;
    const int row0 = blockIdx.y * 64;
    const int col0 = blockIdx.x * 64;
    const int wr = (wave >> 1) * 32;
    const int wc = (wave & 1) * 32;

    // staging lane coords: each gload_lds instr covers 8 rows x 8 chunks(16B)
    const int rl = lane >> 3;   // row within 8-row group
    const int cl = lane & 7;    // chunk within row

    f32x4 acc[2][2] = {};

    for (int kt = 0; kt < Kd; kt += 64) {
        __syncthreads();
#pragma unroll
        for (int h = 0; h < 2; ++h) {
            const int rbase = wave * 16 + h * 8;
            const int rA = rbase + rl;
            // LDS[r][c] <- global[r][c ^ (r&7)]  (pre-swizzled source)
            const _Float16* srcA = A + (size_t)(row0 + rA) * Kd + kt + ((cl ^ (rA & 7)) * 8);
            const _Float16* srcB = B + (size_t)(col0 + rA) * Kd + kt + ((cl ^ (rA & 7)) * 8);
            __builtin_amdgcn_global_load_lds(
                (const __attribute__((address_space(1))) void*)srcA,
                (__attribute__((address_space(3))) void*)(As + rbase * 64), 16, 0, 0);
            __builtin_amdgcn_global_load_lds(
                (const __attribute__((address_space(1))) void*)srcB,
                (__attribute__((address_space(3))) void*)(Bs + rbase * 64), 16, 0, 0);
        }
        __syncthreads();   // drains vmcnt before LDS reads

#pragma unroll
        for (int kh = 0; kh < 2; ++kh) {
            half8 a[2], b[2];
            const int g = kh * 4 + (lane >> 4);   // global 16B chunk index
#pragma unroll
            for (int i = 0; i < 2; ++i) {
                const int ra = wr + i * 16 + (lane & 15);
                const int rb = wc + i * 16 + (lane & 15);
                a[i] = *(const half8*)(As + ra * 64 + ((g ^ (ra & 7)) * 8));
                b[i] = *(const half8*)(Bs + rb * 64 + ((g ^ (rb & 7)) * 8));
            }
#pragma unroll
            for (int i = 0; i < 2; ++i)
#pragma unroll
                for (int j = 0; j < 2; ++j)
                    acc[i][j] = __builtin_amdgcn_mfma_f32_16x16x32_f16(a[i], b[j], acc[i][j], 0, 0, 0);
        }
    }

    // C/D layout: col = lane&15, row = (lane>>4)*4 + reg
    if (MODE == 0) {
#pragma unroll
        for (int i = 0; i < 2; ++i) {
#pragma unroll
            for (int reg = 0; reg < 4; ++reg) {
                const int r  = row0 + wr + i * 16 + (lane >> 4) * 4 + reg;
                const int bt = r >> 8;
                const int s  = r & 255;
                const int hh = s >> 4;
                const int ww = s & 15;
#pragma unroll
                for (int j = 0; j < 2; ++j) {
                    const float v     = acc[i][j][reg];
                    const float other = __shfl_xor(v, 1);   // partner element of RoPE pair
                    const int n    = col0 + wc + j * 16 + (lane & 15);
                    const int sec  = n >> 10;       // 0=q,1=k,2=v
                    const int oi   = n & 1023;
                    const int head = oi >> 6;
                    const int d    = oi & 63;
                    const size_t dst = (((size_t)(bt * NH + head)) * SEQ + s) * DH + d;
                    if (sec == 2) {
                        vb[dst] = v;
                    } else {
                        const int de  = d & ~1;
                        const int j2  = (de < 32) ? (de >> 1) : ((de - 32) >> 1);
                        const float pos = (de < 32) ? (-1.f + hh * (2.f / 15.f))
                                                    : (-1.f + ww * (2.f / 15.f));
                        const float f  = pos * (PI_F * (1.f + j2 * (127.f / 15.f)));
                        const float cf = __cosf(f), sf = __sinf(f);
                        const float res = (d & 1) ? (v * cf + other * sf)
                                                  : (v * cf - other * sf);
                        float* dp = (sec == 0) ? qb : kb;
                        dp[dst] = res;
                    }
                }
            }
        }
    } else {
#pragma unroll
        for (int i = 0; i < 2; ++i)
#pragma unroll
            for (int reg = 0; reg < 4; ++reg) {
                const int r = row0 + wr + i * 16 + (lane >> 4) * 4 + reg;
#pragma unroll
                for (int j = 0; j < 2; ++j) {
                    const int n = col0 + wc + j * 16 + (lane & 15);
                    out[(size_t)r * N + n] = acc[i][j][reg] + bias[n];
                }
            }
    }
}

// ---------------------------------------------------------------------------
// Top-k gathered attention. One wave per query. Phase 1: lanes over keys.
// Phase 2: lanes over d, coalesced v gathers. Fuses +out_not_top_k and the
// transpose to (bt, s, head*64+d); writes fp16 for the out-projection.
// ---------------------------------------------------------------------------
__global__ __launch_bounds__(256)
void attn_topk_kernel(const float* __restrict__ qb, const float* __restrict__ kb,
                      const float* __restrict__ vb, const int* __restrict__ topk,
                      const float* __restrict__ ontk, _Float16* __restrict__ attn_out)
{
    __shared__ float2 pk[4][KTOP];

    const int wave = threadIdx.x >> 6;
    const int lane = threadIdx.x & 63;
    const int gq   = blockIdx.x * 4 + wave;
    const int bt   = gq >> 12;
    const int hs   = gq & 4095;
    const int head = hs >> 8;
    const int s    = hs & 255;

    const float* qrow  = qb + (size_t)gq * DH;
    const float* kbase = kb + ((size_t)(bt * NH + head)) * SEQ * DH;
    const float* vbase = vb + ((size_t)(bt * NH + head)) * SEQ * DH;
    const int*   idxp  = topk + (size_t)gq * KTOP;

    float qr[DH];
#pragma unroll
    for (int i = 0; i < DH / 4; ++i) {
        const float4 t = *(const float4*)(qrow + i * 4);
        qr[i * 4 + 0] = t.x; qr[i * 4 + 1] = t.y;
        qr[i * 4 + 2] = t.z; qr[i * 4 + 3] = t.w;
    }

    float sc[3];
    int   kidx[3];
#pragma unroll
    for (int t = 0; t < 3; ++t) {
        const int kk = lane + t * 64;
        if (kk < KTOP) {
            const int ki = idxp[kk];
            kidx[t] = ki;
            const float4* krow = (const float4*)(kbase + (size_t)ki * DH);
            float dot = 0.f;
#pragma unroll
            for (int i = 0; i < DH / 4; ++i) {
                const float4 kv = krow[i];
                dot += qr[i * 4 + 0] * kv.x + qr[i * 4 + 1] * kv.y +
                       qr[i * 4 + 2] * kv.z + qr[i * 4 + 3] * kv.w;
            }
            sc[t] = dot * 0.125f;
        } else {
            sc[t] = -1e30f;
            kidx[t] = 0;
        }
    }

    float m = fmaxf(fmaxf(sc[0], sc[1]), sc[2]);
#pragma unroll
    for (int off = 32; off; off >>= 1) m = fmaxf(m, __shfl_xor(m, off));
    const float e0 = __expf(sc[0] - m);
    const float e1 = __expf(sc[1] - m);
    const float e2 = (lane < 16) ? __expf(sc[2] - m) : 0.f;
    float ssum = e0 + e1 + e2;
#pragma unroll
    for (int off = 32; off; off >>= 1) ssum += __shfl_xor(ssum, off);
    const float inv = 1.f / ssum;

    pk[wave][lane]      = make_float2(e0 * inv, __int_as_float(kidx[0]));
    pk[wave][lane + 64] = make_float2(e1 * inv, __int_as_float(kidx[1]));
    if (lane < 16)
        pk[wave][lane + 128] = make_float2(e2 * inv, __int_as_float(kidx[2]));
    __syncthreads();

    float acc = ontk[(size_t)gq * DH + lane];
#pragma unroll 4
    for (int kk = 0; kk < KTOP; ++kk) {
        const float2 pi = pk[wave][kk];
        acc += pi.x * vbase[(size_t)__float_as_int(pi.y) * DH + lane];
    }
    attn_out[((size_t)bt * SEQ + s) * DIMF + head * DH + lane] = (_Float16)acc;
}

// ---------------------------------------------------------------------------
extern "C" void kernel_launch(void* const* d_in, const int* in_sizes, int n_in,
                              void* d_out, int out_size, void* d_ws, size_t ws_size,
                              hipStream_t stream) {
    const float* x     = (const float*)d_in[0];
    const float* w_qkv = (const float*)d_in[1];
    const float* w_out = (const float*)d_in[2];
    const float* b_out = (const float*)d_in[3];
    const float* ontk  = (const float*)d_in[4];
    const int*   topk  = (const int*)d_in[5];
    float* out = (float*)d_out;

    const size_t QKV_ELEMS = (size_t)BTN * NH * SEQ * DH;   // 524288

    // workspace layout (~16 MB):
    float* qb = (float*)d_ws;
    float* kb = qb + QKV_ELEMS;
    float* vb = kb + QKV_ELEMS;
    _Float16* xh    = (_Float16*)(vb + QKV_ELEMS);
    _Float16* wqh   = xh + 524288;
    _Float16* woh   = wqh + 3145728;
    _Float16* attnh = woh + 1048576;

    // 1) fp32->fp16 for x, w_qkv, w_out
    cvt3_kernel<<<(N0Q + N1Q + N2Q) / 256, 256, 0, stream>>>(x, w_qkv, w_out, xh, wqh, woh);

    // 2) qkv projection (512x3072, K=1024) + RoPE + scatter
    gemm_f16_kernel<0, DIMF><<<dim3(3072 / 64, 512 / 64), 256, 0, stream>>>(
        xh, wqh, 3072, qb, kb, vb, nullptr, nullptr);

    // 3) gathered top-k attention -> fp16 (bt, s, head*64+d)
    attn_topk_kernel<<<8192 / 4, 256, 0, stream>>>(qb, kb, vb, topk, ontk, attnh);

    // 4) output projection (512x1024, K=1024) + bias
    gemm_f16_kernel<1, DIMF><<<dim3(1024 / 64, 512 / 64), 256, 0, stream>>>(
        attnh, woh, 1024, nullptr, nullptr, nullptr, b_out, out);
}

// Round 3
// 50.493 us; speedup vs baseline: 3.8008x; 1.9859x over previous
//
#include <hip/hip_runtime.h>
#include <hip/hip_bf16.h>
#include <math.h>

// SpatialAxialAttention: B*T=2, H=W=16, dim=1024, HEADS=16, DIM_HEAD=64, K=144
#define BTN   2
#define NH    16
#define SEQ   256
#define DH    64
#define DIMF  1024
#define KTOP  144
#define QT    32
#define PI_F  3.14159265358979323846f

typedef _Float16 half8 __attribute__((ext_vector_type(8)));
typedef _Float16 half4v __attribute__((ext_vector_type(4)));
typedef float f32x4 __attribute__((ext_vector_type(4)));

#define GLDS(src, dst) __builtin_amdgcn_global_load_lds( \
        (const __attribute__((address_space(1))) void*)(src), \
        (__attribute__((address_space(3))) void*)(dst), 16, 0, 0)

// ---------------------------------------------------------------------------
// fp32 -> fp16 conversion for x, w_qkv, w_out
// ---------------------------------------------------------------------------
#define N0Q (524288 / 4)
#define N1Q (3145728 / 4)
#define N2Q (1048576 / 4)
__global__ __launch_bounds__(256)
void cvt3_kernel(const float* __restrict__ a, const float* __restrict__ b,
                 const float* __restrict__ c,
                 _Float16* __restrict__ da, _Float16* __restrict__ db,
                 _Float16* __restrict__ dc)
{
    int q = blockIdx.x * 256 + threadIdx.x;
    const float* s; _Float16* d; int off;
    if (q < N0Q)            { s = a; d = da; off = q; }
    else if (q < N0Q + N1Q) { s = b; d = db; off = q - N0Q; }
    else                    { s = c; d = dc; off = q - (N0Q + N1Q); }
    const float4 v = *(const float4*)(s + (size_t)off * 4);
    half4v h;
    h[0] = (_Float16)v.x; h[1] = (_Float16)v.y;
    h[2] = (_Float16)v.z; h[3] = (_Float16)v.w;
    *(half4v*)(d + (size_t)off * 4) = h;
}

// ---------------------------------------------------------------------------
// fp16 MFMA NT-GEMM (64x64 tile, BK=64, 4 waves, 2x2 frags/wave).
// MODE 0: epilogue splits qkv, RoPE on q,k -> fp16 (bt,head,s,d);
//         v -> fp16 TRANSPOSED (bt,head,d,s). MODE 1: +bias fp32 store.
// ---------------------------------------------------------------------------
template <int MODE, int Kd>
__global__ __launch_bounds__(256)
void gemm_f16_kernel(const _Float16* __restrict__ A, const _Float16* __restrict__ B,
                     int N,
                     _Float16* __restrict__ qb, _Float16* __restrict__ kb,
                     _Float16* __restrict__ vb,
                     const float* __restrict__ bias, float* __restrict__ out)
{
    __shared__ __align__(16) _Float16 As[64 * 64];
    __shared__ __align__(16) _Float16 Bs[64 * 64];

    const int tid  = threadIdx.x;
    const int wave = tid >> 6;
    const int lane = tid & 63;
    const int row0 = blockIdx.y * 64;
    const int col0 = blockIdx.x * 64;
    const int wr = (wave >> 1) * 32;
    const int wc = (wave & 1) * 32;
    const int rl = lane >> 3;
    const int cl = lane & 7;

    f32x4 acc[2][2] = {};

    for (int kt = 0; kt < Kd; kt += 64) {
        __syncthreads();
#pragma unroll
        for (int h = 0; h < 2; ++h) {
            const int rbase = wave * 16 + h * 8;
            const int rA = rbase + rl;
            const _Float16* srcA = A + (size_t)(row0 + rA) * Kd + kt + ((cl ^ (rA & 7)) * 8);
            const _Float16* srcB = B + (size_t)(col0 + rA) * Kd + kt + ((cl ^ (rA & 7)) * 8);
            GLDS(srcA, As + rbase * 64);
            GLDS(srcB, Bs + rbase * 64);
        }
        __syncthreads();

#pragma unroll
        for (int kh = 0; kh < 2; ++kh) {
            half8 a[2], b[2];
            const int g = kh * 4 + (lane >> 4);
#pragma unroll
            for (int i = 0; i < 2; ++i) {
                const int ra = wr + i * 16 + (lane & 15);
                const int rb = wc + i * 16 + (lane & 15);
                a[i] = *(const half8*)(As + ra * 64 + ((g ^ (ra & 7)) * 8));
                b[i] = *(const half8*)(Bs + rb * 64 + ((g ^ (rb & 7)) * 8));
            }
#pragma unroll
            for (int i = 0; i < 2; ++i)
#pragma unroll
                for (int j = 0; j < 2; ++j)
                    acc[i][j] = __builtin_amdgcn_mfma_f32_16x16x32_f16(a[i], b[j], acc[i][j], 0, 0, 0);
        }
    }

    if (MODE == 0) {
#pragma unroll
        for (int i = 0; i < 2; ++i) {
#pragma unroll
            for (int reg = 0; reg < 4; ++reg) {
                const int r  = row0 + wr + i * 16 + (lane >> 4) * 4 + reg;
                const int bt = r >> 8;
                const int s  = r & 255;
                const int hh = s >> 4;
                const int ww = s & 15;
#pragma unroll
                for (int j = 0; j < 2; ++j) {
                    const float v     = acc[i][j][reg];
                    const float other = __shfl_xor(v, 1);
                    const int n    = col0 + wc + j * 16 + (lane & 15);
                    const int sec  = n >> 10;
                    const int oi   = n & 1023;
                    const int head = oi >> 6;
                    const int d    = oi & 63;
                    if (sec == 2) {
                        vb[(((size_t)(bt * NH + head)) * DH + d) * SEQ + s] = (_Float16)v;
                    } else {
                        const int de  = d & ~1;
                        const int j2  = (de < 32) ? (de >> 1) : ((de - 32) >> 1);
                        const float pos = (de < 32) ? (-1.f + hh * (2.f / 15.f))
                                                    : (-1.f + ww * (2.f / 15.f));
                        const float f  = pos * (PI_F * (1.f + j2 * (127.f / 15.f)));
                        const float cf = __cosf(f), sf = __sinf(f);
                        const float res = (d & 1) ? (v * cf + other * sf)
                                                  : (v * cf - other * sf);
                        _Float16* dp = (sec == 0) ? qb : kb;
                        dp[(((size_t)(bt * NH + head)) * SEQ + s) * DH + d] = (_Float16)res;
                    }
                }
            }
        }
    } else {
#pragma unroll
        for (int i = 0; i < 2; ++i)
#pragma unroll
            for (int reg = 0; reg < 4; ++reg) {
                const int r = row0 + wr + i * 16 + (lane >> 4) * 4 + reg;
#pragma unroll
                for (int j = 0; j < 2; ++j) {
                    const int n = col0 + wc + j * 16 + (lane & 15);
                    out[(size_t)r * N + n] = acc[i][j][reg] + bias[n];
                }
            }
    }
}

// ---------------------------------------------------------------------------
// Dense-score top-k attention. One block per (bt, head, 32-query tile),
// 8 waves. Phase A: S = Q.K^T (MFMA, full 256 keys). Phase B: per query,
// gather 144 scalar scores from LDS, shuffle softmax, scatter-add probs
// into a dense P row (LDS atomicAdd handles duplicate indices).
// Phase C: out = P.V (MFMA) + ontk, store fp16 (bt, s, head*64+d).
// ---------------------------------------------------------------------------
__global__ __launch_bounds__(512)
void attn_dense_kernel(const _Float16* __restrict__ qh, const _Float16* __restrict__ kh,
                       const _Float16* __restrict__ vt, const int* __restrict__ topk,
                       const float* __restrict__ ontk, _Float16* __restrict__ attnh)
{
    __shared__ __align__(16) _Float16 Qs[QT * DH];      // 4 KB
    __shared__ __align__(16) _Float16 Ks[SEQ * DH];     // 32 KB
    __shared__ __align__(16) _Float16 VTs[DH * SEQ];    // 32 KB
    __shared__ __align__(16) float    Ps[QT * 260];     // 33.3 KB (scores, then probs)

    const int tid  = threadIdx.x;
    const int w    = tid >> 6;
    const int lane = tid & 63;
    const int bid  = blockIdx.x;
    const int bt   = bid >> 7;
    const int head = (bid >> 3) & 15;
    const int s0   = (bid & 7) * QT;

    const _Float16* kbase  = kh + ((size_t)(bt * NH + head)) * SEQ * DH;
    const _Float16* vtbase = vt + ((size_t)(bt * NH + head)) * DH * SEQ;
    const _Float16* qbase  = qh + (((size_t)(bt * NH + head)) * SEQ + s0) * DH;

    // ---- stage K (8 rows x 8 chunks per instr, chunk-swizzled source) ----
#pragma unroll
    for (int h = 0; h < 4; ++h) {
        const int r = w * 32 + h * 8 + (lane >> 3);
        GLDS(kbase + (size_t)r * DH + (((lane & 7) ^ (r & 7)) * 8), Ks + (w * 32 + h * 8) * DH);
    }
    // ---- stage VT (2 rows x 32 chunks per instr) ----
#pragma unroll
    for (int h = 0; h < 4; ++h) {
        const int r = w * 8 + h * 2 + (lane >> 5);
        GLDS(vtbase + (size_t)r * SEQ + (((lane & 31) ^ (r & 7)) * 8), VTs + (w * 8 + h * 2) * SEQ);
    }
    // ---- stage Q ----
    if (w < 4) {
        const int r = w * 8 + (lane >> 3);
        GLDS(qbase + (size_t)r * DH + (((lane & 7) ^ (r & 7)) * 8), Qs + (w * 8) * DH);
    }
    __syncthreads();

    // ---- Phase A: S[32][256], wave w owns cols w*32..w*32+31 ----
    f32x4 acc[2][2] = {};
#pragma unroll
    for (int kk = 0; kk < 2; ++kk) {
        half8 a[2], b[2];
        const int c = kk * 4 + (lane >> 4);
#pragma unroll
        for (int i = 0; i < 2; ++i) {
            const int ra = i * 16 + (lane & 15);
            const int rb = w * 32 + i * 16 + (lane & 15);
            a[i] = *(const half8*)(Qs + ra * DH + ((c ^ (ra & 7)) * 8));
            b[i] = *(const half8*)(Ks + rb * DH + ((c ^ (rb & 7)) * 8));
        }
#pragma unroll
        for (int i = 0; i < 2; ++i)
#pragma unroll
            for (int j = 0; j < 2; ++j)
                acc[i][j] = __builtin_amdgcn_mfma_f32_16x16x32_f16(a[i], b[j], acc[i][j], 0, 0, 0);
    }
#pragma unroll
    for (int i = 0; i < 2; ++i)
#pragma unroll
        for (int j = 0; j < 2; ++j)
#pragma unroll
            for (int reg = 0; reg < 4; ++reg) {
                const int row = i * 16 + (lane >> 4) * 4 + reg;
                const int col = w * 32 + j * 16 + (lane & 15);
                Ps[row * 260 + col] = acc[i][j][reg];
            }
    __syncthreads();

    // ---- Phase B: softmax + scatter; wave w owns queries w*4..w*4+3 ----
#pragma unroll
    for (int qq = 0; qq < 4; ++qq) {
        const int q = w * 4 + qq;
        const size_t gq = ((size_t)(bt * NH + head)) * SEQ + s0 + q;
        const int* idxp = topk + gq * KTOP;
        const int ki0 = idxp[lane];
        const int ki1 = idxp[lane + 64];
        const int ki2 = (lane < 16) ? idxp[lane + 128] : 0;
        const float sv0 = Ps[q * 260 + ki0] * 0.125f;
        const float sv1 = Ps[q * 260 + ki1] * 0.125f;
        const float sv2 = (lane < 16) ? Ps[q * 260 + ki2] * 0.125f : -1e30f;
        float m = fmaxf(fmaxf(sv0, sv1), sv2);
#pragma unroll
        for (int off = 32; off; off >>= 1) m = fmaxf(m, __shfl_xor(m, off));
        const float e0 = __expf(sv0 - m);
        const float e1 = __expf(sv1 - m);
        const float e2 = (lane < 16) ? __expf(sv2 - m) : 0.f;
        float z = e0 + e1 + e2;
#pragma unroll
        for (int off = 32; off; off >>= 1) z += __shfl_xor(z, off);
        const float inv = 1.f / z;
        // all lanes' score reads above precede these stores (lockstep wave,
        // same LDS array -> compiler keeps load/store order)
        for (int c2 = lane; c2 < 260; c2 += 64) Ps[q * 260 + c2] = 0.f;
        atomicAdd(&Ps[q * 260 + ki0], e0 * inv);
        atomicAdd(&Ps[q * 260 + ki1], e1 * inv);
        if (lane < 16) atomicAdd(&Ps[q * 260 + ki2], e2 * inv);
    }
    __syncthreads();

    // ---- Phase C: out[32][64] = P.V ; wave w -> frag (w>>2, w&3) ----
    const int iw = w >> 2;
    const int jw = w & 3;
    f32x4 oacc = {};
#pragma unroll
    for (int ks = 0; ks < 8; ++ks) {
        const int ra = iw * 16 + (lane & 15);
        const float* pp = Ps + ra * 260 + ks * 32 + (lane >> 4) * 8;
        const float4 p0 = *(const float4*)pp;
        const float4 p1 = *(const float4*)(pp + 4);
        half8 af;
        af[0] = (_Float16)p0.x; af[1] = (_Float16)p0.y;
        af[2] = (_Float16)p0.z; af[3] = (_Float16)p0.w;
        af[4] = (_Float16)p1.x; af[5] = (_Float16)p1.y;
        af[6] = (_Float16)p1.z; af[7] = (_Float16)p1.w;
        const int d = jw * 16 + (lane & 15);
        const int c = ks * 4 + (lane >> 4);
        const half8 bf = *(const half8*)(VTs + d * SEQ + ((c ^ (d & 7)) * 8));
        oacc = __builtin_amdgcn_mfma_f32_16x16x32_f16(af, bf, oacc, 0, 0, 0);
    }
#pragma unroll
    for (int reg = 0; reg < 4; ++reg) {
        const int row = iw * 16 + (lane >> 4) * 4 + reg;
        const int d   = jw * 16 + (lane & 15);
        const int s   = s0 + row;
        const float v = oacc[reg] +
            ontk[(((size_t)(bt * NH + head)) * SEQ + s) * DH + d];
        attnh[((size_t)(bt * SEQ + s)) * DIMF + head * DH + d] = (_Float16)v;
    }
}

// ---------------------------------------------------------------------------
extern "C" void kernel_launch(void* const* d_in, const int* in_sizes, int n_in,
                              void* d_out, int out_size, void* d_ws, size_t ws_size,
                              hipStream_t stream) {
    const float* x     = (const float*)d_in[0];
    const float* w_qkv = (const float*)d_in[1];
    const float* w_out = (const float*)d_in[2];
    const float* b_out = (const float*)d_in[3];
    const float* ontk  = (const float*)d_in[4];
    const int*   topk  = (const int*)d_in[5];
    float* out = (float*)d_out;

    const size_t QE = (size_t)BTN * NH * SEQ * DH;   // 524288

    _Float16* xh    = (_Float16*)d_ws;
    _Float16* wqh   = xh + 524288;
    _Float16* woh   = wqh + 3145728;
    _Float16* attnh = woh + 1048576;
    _Float16* qhb   = attnh + QE;
    _Float16* khb   = qhb + QE;
    _Float16* vtb   = khb + QE;

    // 1) fp32->fp16 inputs
    cvt3_kernel<<<(N0Q + N1Q + N2Q) / 256, 256, 0, stream>>>(x, w_qkv, w_out, xh, wqh, woh);

    // 2) qkv projection + RoPE -> fp16 q,k (bt,head,s,d); v^T (bt,head,d,s)
    gemm_f16_kernel<0, DIMF><<<dim3(3072 / 64, 512 / 64), 256, 0, stream>>>(
        xh, wqh, 3072, qhb, khb, vtb, nullptr, nullptr);

    // 3) dense-score top-k attention
    attn_dense_kernel<<<BTN * NH * (SEQ / QT), 512, 0, stream>>>(
        qhb, khb, vtb, topk, ontk, attnh);

    // 4) output projection + bias
    gemm_f16_kernel<1, DIMF><<<dim3(1024 / 64, 512 / 64), 256, 0, stream>>>(
        attnh, woh, 1024, nullptr, nullptr, nullptr, b_out, out);
}